// Round 2
// baseline (23080.960 us; speedup 1.0000x reference)
//
#include <hip/hip_runtime.h>

#define T_STEPS 512
#define E_EDGES 128
#define NN 32
#define HH 256
#define G4 1024   // 4*H
#define NWG 64    // 2 dirs * 32 slots
#define TPB 512

__device__ __forceinline__ float fsig(float x) {
  x = fminf(fmaxf(x, -30.f), 30.f);
  return 1.f / (1.f + __expf(-x));
}
__device__ __forceinline__ float ftanh(float x) {
  float xc = fminf(fmaxf(x, -15.f), 15.f);
  float e = __expf(2.f * xc);
  return (e - 1.f) / (e + 1.f);
}

// ---------------- per-step edge counts (denominators) ----------------
__global__ __launch_bounds__(128) void count_kernel(const int* __restrict__ src,
    const int* __restrict__ dst, float* __restrict__ cS, float* __restrict__ cD) {
  __shared__ int ls[NN], ld[NN];
  int t = blockIdx.x;
  if (threadIdx.x < NN) { ls[threadIdx.x] = 0; ld[threadIdx.x] = 0; }
  __syncthreads();
  atomicAdd(&ls[src[t * E_EDGES + threadIdx.x]], 1);
  atomicAdd(&ld[dst[t * E_EDGES + threadIdx.x]], 1);
  __syncthreads();
  if (threadIdx.x < NN) {
    cS[t * NN + threadIdx.x] = (float)ls[threadIdx.x];
    cD[t * NN + threadIdx.x] = (float)ld[threadIdx.x];
  }
}

// ---------------- feed-forward gates GEMM -----------------------------
// Gx[lt][k][e] = b[k] + sum_m In[tsrc][e][m] * W[k][m]
template <int M>
__global__ __launch_bounds__(256) void gates_gemm(
    const float* __restrict__ In, const float* __restrict__ W,
    const float* __restrict__ b, float* __restrict__ Gx, int reverse, int t0) {
  __shared__ float Wsh[64][68];
  __shared__ float Xsh[128][68];
  const int tid = threadIdx.x;
  const int k0 = blockIdx.x * 64;
  const int lt = blockIdx.y;
  const int t = t0 + lt;
  const int tsrc = reverse ? (T_STEPS - 1 - t) : t;
  const float* Inb = In + (size_t)tsrc * E_EDGES * M;

  const int ty = tid >> 4;  // 0..15 -> k group
  const int tx = tid & 15;  // 0..15 -> e group (strided e = tx + 16*j)

  float acc[4][8];
#pragma unroll
  for (int i = 0; i < 4; ++i) {
    float bv = b[k0 + ty * 4 + i];
#pragma unroll
    for (int j = 0; j < 8; ++j) acc[i][j] = bv;
  }

  for (int m0 = 0; m0 < M; m0 += 64) {
    __syncthreads();
#pragma unroll
    for (int p = 0; p < 4; ++p) {
      int r = (tid >> 4) + 16 * p;
      int c4 = tid & 15;
      float4 v = *(const float4*)(W + (size_t)(k0 + r) * M + m0 + c4 * 4);
      *(float4*)(&Wsh[r][c4 * 4]) = v;
    }
#pragma unroll
    for (int p = 0; p < 8; ++p) {
      int r = (tid >> 4) + 16 * p;
      int c4 = tid & 15;
      float4 v = *(const float4*)(Inb + (size_t)r * M + m0 + c4 * 4);
      *(float4*)(&Xsh[r][c4 * 4]) = v;
    }
    __syncthreads();
#pragma unroll 8
    for (int mm = 0; mm < 64; ++mm) {
      float wv[4], xv[8];
#pragma unroll
      for (int i = 0; i < 4; ++i) wv[i] = Wsh[ty * 4 + i][mm];
#pragma unroll
      for (int j = 0; j < 8; ++j) xv[j] = Xsh[tx + 16 * j][mm];
#pragma unroll
      for (int i = 0; i < 4; ++i)
#pragma unroll
        for (int j = 0; j < 8; ++j) acc[i][j] = __fmaf_rn(wv[i], xv[j], acc[i][j]);
    }
  }
#pragma unroll
  for (int i = 0; i < 4; ++i) {
    size_t rowo = ((size_t)lt * G4 + (k0 + ty * 4 + i)) * E_EDGES;
#pragma unroll
    for (int j = 0; j < 8; ++j) Gx[rowo + tx + 16 * j] = acc[i][j];
  }
}

// ---------------- recurrence (cooperative, both directions) -----------
// 64 WGs x 512 threads. WG owns 8 hidden channels (j0..j0+7) of one direction.
// hn exchange via global, DOUBLE-BUFFERED by step parity (fixes the
// write-before-read race across WGs within a step).
__global__ __launch_bounds__(TPB) void recur_kernel(
    const float* __restrict__ GxF, const float* __restrict__ GxB,
    const float* __restrict__ WhhF, const float* __restrict__ WhhB,
    const int* __restrict__ src, const int* __restrict__ dst,
    const float* __restrict__ cS, const float* __restrict__ cD,
    float* hnG, float* cnG, float* outBase,
    int t0, int nsteps, int roundBase, int* barCnt, int* barEpoch) {
  __shared__ float WsT[HH][36];   // transposed Whh slice: WsT[k][gc]
  __shared__ float hnT[HH][36];   // transposed node h:   hnT[k][n]
  __shared__ float zP[8][NN][33]; // per-wave z partials
  __shared__ float zF[NN][33];    // final z
  __shared__ float cnL[NN][9];
  __shared__ float hAcc[NN][9];
  __shared__ float cAcc[NN][9];

  const int tid = threadIdx.x;
  const int wg = blockIdx.x;
  const int dir = wg >> 5;
  const int slot = wg & 31;
  const int j0 = slot * 8;
  const float* Gx = dir ? GxB : GxF;
  const float* Whh = dir ? WhhB : WhhF;
  const int* seA = dir ? dst : src;
  const int* deA = dir ? src : dst;
  const float* cA = dir ? cS : cD;
  float* cnGd = cnG + (size_t)dir * NN * HH;

  // --- load WsT once: WsT[k][gc] = Whh[g*256 + j0 + jj][k], gc = g*8+jj ---
  {
    int gc = tid & 31, g = gc >> 3, jj = gc & 7;
    int c4 = tid >> 5;  // 0..15
    const float* wrow = Whh + (size_t)(g * HH + j0 + jj) * HH;
#pragma unroll
    for (int p = 0; p < 4; ++p) {
      int idx = c4 + p * 16;
      float4 v = *(const float4*)(wrow + idx * 4);
      WsT[idx * 4 + 0][gc] = v.x; WsT[idx * 4 + 1][gc] = v.y;
      WsT[idx * 4 + 2][gc] = v.z; WsT[idx * 4 + 3][gc] = v.w;
    }
  }
  if (tid < 256) {
    int n = tid >> 3, jj = tid & 7;
    cnL[n][jj] = cnGd[n * HH + j0 + jj];
    hAcc[n][jj] = 0.f; cAcc[n][jj] = 0.f;
  }

  const int e = tid >> 2, q = tid & 3;   // edge phase mapping
  const int ns = (tid >> 3) & 31;        // node for count prefetch
  const int lane = tid & 63, kg = tid >> 6;  // z phase: wave kg handles K slice
  const int zn0 = (lane & 3) * 8;
  const int zg0 = (lane >> 2) * 2;

  // --- prefetch step 0 ---
  int sec, dec; float cntc; float gxc[8];
  {
    int tv = dir ? (T_STEPS - 1 - t0) : t0;
    sec = seA[tv * E_EDGES + e];
    dec = deA[tv * E_EDGES + e];
    cntc = cA[tv * NN + ns];
    const float* gp = Gx + e;
#pragma unroll
    for (int g = 0; g < 4; ++g) {
      gxc[g * 2 + 0] = gp[(size_t)(g * HH + j0 + 2 * q + 0) * E_EDGES];
      gxc[g * 2 + 1] = gp[(size_t)(g * HH + j0 + 2 * q + 1) * E_EDGES];
    }
  }
  __syncthreads();

  for (int rl = 0; rl < nsteps; ++rl) {
    const int r = t0 + rl;
    // --- prefetch next step (HBM latency hides under this step's body) ---
    int sep, dep; float cntp; float gxp[8];
    {
      int rc = (rl + 1 < nsteps) ? (rl + 1) : rl;
      int tv = dir ? (T_STEPS - 1 - (t0 + rc)) : (t0 + rc);
      sep = seA[tv * E_EDGES + e];
      dep = deA[tv * E_EDGES + e];
      cntp = cA[tv * NN + ns];
      const float* gp = Gx + (size_t)rc * (G4 * E_EDGES) + e;
#pragma unroll
      for (int g = 0; g < 4; ++g) {
        gxp[g * 2 + 0] = gp[(size_t)(g * HH + j0 + 2 * q + 0) * E_EDGES];
        gxp[g * 2 + 1] = gp[(size_t)(g * HH + j0 + 2 * q + 1) * E_EDGES];
      }
    }
    // --- stage hn (transposed) from parity buffer ---
    {
      const float* hnRd = hnG + (size_t)((r & 1) * 2 + dir) * NN * HH;
      int n = tid >> 4, c4 = tid & 15;
#pragma unroll
      for (int p = 0; p < 4; ++p) {
        int idx = c4 + p * 16;
        float4 v = *(const float4*)(hnRd + n * HH + idx * 4);
        hnT[idx * 4 + 0][n] = v.x; hnT[idx * 4 + 1][n] = v.y;
        hnT[idx * 4 + 2][n] = v.z; hnT[idx * 4 + 3][n] = v.w;
      }
    }
    __syncthreads();

    // --- z = hn @ Whh_slice^T (one wave per K-group of 32) ---
    float acc[8][2];
#pragma unroll
    for (int i = 0; i < 8; ++i) { acc[i][0] = 0.f; acc[i][1] = 0.f; }
#pragma unroll 4
    for (int kk = 0; kk < 32; ++kk) {
      int k = kg * 32 + kk;
      float4 ha = *(const float4*)&hnT[k][zn0];
      float4 hb = *(const float4*)&hnT[k][zn0 + 4];
      float2 wv = *(const float2*)&WsT[k][zg0];
      acc[0][0] = __fmaf_rn(ha.x, wv.x, acc[0][0]); acc[0][1] = __fmaf_rn(ha.x, wv.y, acc[0][1]);
      acc[1][0] = __fmaf_rn(ha.y, wv.x, acc[1][0]); acc[1][1] = __fmaf_rn(ha.y, wv.y, acc[1][1]);
      acc[2][0] = __fmaf_rn(ha.z, wv.x, acc[2][0]); acc[2][1] = __fmaf_rn(ha.z, wv.y, acc[2][1]);
      acc[3][0] = __fmaf_rn(ha.w, wv.x, acc[3][0]); acc[3][1] = __fmaf_rn(ha.w, wv.y, acc[3][1]);
      acc[4][0] = __fmaf_rn(hb.x, wv.x, acc[4][0]); acc[4][1] = __fmaf_rn(hb.x, wv.y, acc[4][1]);
      acc[5][0] = __fmaf_rn(hb.y, wv.x, acc[5][0]); acc[5][1] = __fmaf_rn(hb.y, wv.y, acc[5][1]);
      acc[6][0] = __fmaf_rn(hb.z, wv.x, acc[6][0]); acc[6][1] = __fmaf_rn(hb.z, wv.y, acc[6][1]);
      acc[7][0] = __fmaf_rn(hb.w, wv.x, acc[7][0]); acc[7][1] = __fmaf_rn(hb.w, wv.y, acc[7][1]);
    }
#pragma unroll
    for (int i = 0; i < 8; ++i) {
      zP[kg][zn0 + i][zg0] = acc[i][0];
      zP[kg][zn0 + i][zg0 + 1] = acc[i][1];
    }
    __syncthreads();
    {
      int n = tid >> 4, gc0 = (tid & 15) * 2;
      float s0 = 0.f, s1 = 0.f;
#pragma unroll
      for (int g2 = 0; g2 < 8; ++g2) { s0 += zP[g2][n][gc0]; s1 += zP[g2][n][gc0 + 1]; }
      zF[n][gc0] = s0; zF[n][gc0 + 1] = s1;
    }
    __syncthreads();

    // --- edge phase: gates -> cell -> per-edge h ---
    {
      const float* zr = zF[sec];
      const float* cr = cnL[sec];
      float hu[2];
#pragma unroll
      for (int u = 0; u < 2; ++u) {
        int jj = 2 * q + u;
        float gi = gxc[0 + u] + zr[jj];
        float gf = gxc[2 + u] + zr[8 + jj];
        float gg = gxc[4 + u] + zr[16 + jj];
        float go = gxc[6 + u] + zr[24 + jj];
        float cv = fsig(gf) * cr[jj] + fsig(gi) * ftanh(gg);
        float hv = fsig(go) * ftanh(cv);
        hu[u] = hv;
        atomicAdd(&hAcc[dec][jj], hv);
        atomicAdd(&cAcc[dec][jj], cv);
      }
      int tw = dir ? (T_STEPS - 1 - r) : r;
      *(float2*)(outBase + ((size_t)tw * E_EDGES + e) * 512 + dir * 256 + j0 + 2 * q)
          = make_float2(hu[0], hu[1]);
    }
    __syncthreads();

    // --- scatter-mean -> write next-parity hn ---
    if (tid < 256) {
      int n = tid >> 3, jj = tid & 7;
      float* hnWr = hnG + (size_t)(((r + 1) & 1) * 2 + dir) * NN * HH;
      float denom = fmaxf(cntc, 1.f);
      hnWr[n * HH + j0 + jj] = hAcc[n][jj] / denom;
      cnL[n][jj] = cAcc[n][jj] / denom;
      hAcc[n][jj] = 0.f; cAcc[n][jj] = 0.f;
    }
    __threadfence();
    __syncthreads();

    // --- grid barrier (epoch-based) ---
    if (tid == 0) {
      int target = roundBase + rl + 1;
      int arrived = __hip_atomic_fetch_add(barCnt, 1, __ATOMIC_ACQ_REL, __HIP_MEMORY_SCOPE_AGENT);
      if (arrived == NWG - 1) {
        __hip_atomic_store(barCnt, 0, __ATOMIC_RELAXED, __HIP_MEMORY_SCOPE_AGENT);
        __hip_atomic_store(barEpoch, target, __ATOMIC_RELEASE, __HIP_MEMORY_SCOPE_AGENT);
      } else {
        int guard = 0;
        while (__hip_atomic_load(barEpoch, __ATOMIC_ACQUIRE, __HIP_MEMORY_SCOPE_AGENT) < target) {
          __builtin_amdgcn_s_sleep(1);
          if (++guard > (1 << 24)) break;
        }
      }
      // every WG (releaser included) does an acquire -> L1 invalidated
      (void)__hip_atomic_load(barEpoch, __ATOMIC_ACQUIRE, __HIP_MEMORY_SCOPE_AGENT);
    }
    __syncthreads();

    // rotate prefetched registers
    sec = sep; dec = dep; cntc = cntp;
#pragma unroll
    for (int i2 = 0; i2 < 8; ++i2) gxc[i2] = gxp[i2];
  }

  if (tid < 256) {
    int n = tid >> 3, jj = tid & 7;
    cnGd[n * HH + j0 + jj] = cnL[n][jj];
  }
}

// ---------------- host launcher ---------------------------------------
extern "C" void kernel_launch(void* const* d_in, const int* in_sizes, int n_in,
                              void* d_out, int out_size, void* d_ws, size_t ws_size,
                              hipStream_t stream) {
  const float* x = (const float*)d_in[0];
  const float* Wih0 = (const float*)d_in[1];
  const float* Whh0 = (const float*)d_in[2];
  const float* b0 = (const float*)d_in[3];
  const float* Wih1 = (const float*)d_in[4];
  const float* Whh1 = (const float*)d_in[5];
  const float* b1 = (const float*)d_in[6];
  const int* src = (const int*)d_in[7];
  const int* dst = (const int*)d_in[8];
  float* out = (float*)d_out;

  const size_t outElems = (size_t)T_STEPS * E_EDGES * 512;
  int C = 512;
  while (C >= 1) {
    size_t need = (2 * (size_t)C * G4 * E_EDGES + outElems + 6 * (size_t)NN * HH +
                   2 * (size_t)T_STEPS * NN + 64) * sizeof(float);
    if (need <= ws_size) break;
    C >>= 1;
  }
  if (C < 1) return;

  float* GxF = (float*)d_ws;
  float* GxB = GxF + (size_t)C * G4 * E_EDGES;
  float* out0 = GxB + (size_t)C * G4 * E_EDGES;
  float* hnG = out0 + outElems;                 // 4 * NN*HH (2 parities x 2 dirs)
  float* cnG = hnG + 4 * NN * HH;               // 2 * NN*HH
  float* cSt = cnG + 2 * NN * HH;
  float* cDt = cSt + (size_t)T_STEPS * NN;
  int* bar = (int*)(cDt + (size_t)T_STEPS * NN);

  hipMemsetAsync(bar, 0, 2 * sizeof(int), stream);
  count_kernel<<<dim3(T_STEPS), 128, 0, stream>>>(src, dst, cSt, cDt);

  for (int layer = 0; layer < 2; ++layer) {
    const float* Wih = layer ? Wih1 : Wih0;
    const float* Whh = layer ? Whh1 : Whh0;
    const float* bb = layer ? b1 : b0;
    const float* In = layer ? out0 : x;
    float* outT = layer ? out : out0;
    hipMemsetAsync(hnG, 0, 4 * NN * HH * sizeof(float), stream);
    hipMemsetAsync(cnG, 0, 2 * NN * HH * sizeof(float), stream);
    for (int t0 = 0; t0 < T_STEPS; t0 += C) {
      if (layer == 0) {
        gates_gemm<64><<<dim3(16, C), 256, 0, stream>>>(In, Wih, bb, GxF, 0, t0);
        gates_gemm<64><<<dim3(16, C), 256, 0, stream>>>(In, Wih + (size_t)G4 * 64, bb + G4, GxB, 1, t0);
      } else {
        gates_gemm<512><<<dim3(16, C), 256, 0, stream>>>(In, Wih, bb, GxF, 0, t0);
        gates_gemm<512><<<dim3(16, C), 256, 0, stream>>>(In, Wih + (size_t)G4 * 512, bb + G4, GxB, 1, t0);
      }
      const float* gxF = GxF; const float* gxB = GxB;
      const float* whF = Whh; const float* whB = Whh + (size_t)G4 * HH;
      const int* psrc = src; const int* pdst = dst;
      const float* pcS = cSt; const float* pcD = cDt;
      float* phn = hnG; float* pcn = cnG; float* pout = outT;
      int a_t0 = t0, a_ns = C, a_rb = layer * T_STEPS + t0;
      int* pbc = bar; int* pbe = bar + 1;
      void* args[16] = {&gxF, &gxB, &whF, &whB, &psrc, &pdst, &pcS, &pcD,
                        &phn, &pcn, &pout, &a_t0, &a_ns, &a_rb, &pbc, &pbe};
      hipLaunchCooperativeKernel((const void*)recur_kernel, dim3(NWG), dim3(TPB),
                                 args, 0, stream);
    }
  }
}

// Round 3
// 20862.685 us; speedup vs baseline: 1.1063x; 1.1063x over previous
//
#include <hip/hip_runtime.h>

#define T_STEPS 512
#define E_EDGES 128
#define NN 32
#define HH 256
#define G4 1024   // 4*H
#define NWG 64    // 2 dirs * 32 slots
#define TPB 256
#define FSTRIDE 16  // ints between flags (64B cachelines)

__device__ __forceinline__ float fsig(float x) {
  x = fminf(fmaxf(x, -30.f), 30.f);
  return 1.f / (1.f + __expf(-x));
}
__device__ __forceinline__ float ftanh(float x) {
  float xc = fminf(fmaxf(x, -15.f), 15.f);
  float e = __expf(2.f * xc);
  return (e - 1.f) / (e + 1.f);
}

// ---------------- per-step edge counts (denominators) ----------------
__global__ __launch_bounds__(128) void count_kernel(const int* __restrict__ src,
    const int* __restrict__ dst, float* __restrict__ cS, float* __restrict__ cD) {
  __shared__ int ls[NN], ld[NN];
  int t = blockIdx.x;
  if (threadIdx.x < NN) { ls[threadIdx.x] = 0; ld[threadIdx.x] = 0; }
  __syncthreads();
  atomicAdd(&ls[src[t * E_EDGES + threadIdx.x]], 1);
  atomicAdd(&ld[dst[t * E_EDGES + threadIdx.x]], 1);
  __syncthreads();
  if (threadIdx.x < NN) {
    cS[t * NN + threadIdx.x] = (float)ls[threadIdx.x];
    cD[t * NN + threadIdx.x] = (float)ld[threadIdx.x];
  }
}

// ---------------- feed-forward gates GEMM -----------------------------
// Gx[lt][e][k] = b[k] + sum_m In[tsrc][e][m] * W[k][m]   (note [e][k] layout)
template <int M>
__global__ __launch_bounds__(256) void gates_gemm(
    const float* __restrict__ In, const float* __restrict__ W,
    const float* __restrict__ b, float* __restrict__ Gx, int reverse, int t0) {
  __shared__ float Wsh[64][68];
  __shared__ float Xsh[128][68];
  const int tid = threadIdx.x;
  const int k0 = blockIdx.x * 64;
  const int lt = blockIdx.y;
  const int t = t0 + lt;
  const int tsrc = reverse ? (T_STEPS - 1 - t) : t;
  const float* Inb = In + (size_t)tsrc * E_EDGES * M;

  const int ty = tid >> 4;  // 0..15 -> k group (k = k0 + ty*4 + i)
  const int tx = tid & 15;  // 0..15 -> e group (e = tx + 16*j)

  float acc[4][8];
#pragma unroll
  for (int i = 0; i < 4; ++i) {
    float bv = b[k0 + ty * 4 + i];
#pragma unroll
    for (int j = 0; j < 8; ++j) acc[i][j] = bv;
  }

  for (int m0 = 0; m0 < M; m0 += 64) {
    __syncthreads();
#pragma unroll
    for (int p = 0; p < 4; ++p) {
      int r = (tid >> 4) + 16 * p;
      int c4 = tid & 15;
      float4 v = *(const float4*)(W + (size_t)(k0 + r) * M + m0 + c4 * 4);
      *(float4*)(&Wsh[r][c4 * 4]) = v;
    }
#pragma unroll
    for (int p = 0; p < 8; ++p) {
      int r = (tid >> 4) + 16 * p;
      int c4 = tid & 15;
      float4 v = *(const float4*)(Inb + (size_t)r * M + m0 + c4 * 4);
      *(float4*)(&Xsh[r][c4 * 4]) = v;
    }
    __syncthreads();
#pragma unroll 8
    for (int mm = 0; mm < 64; ++mm) {
      float wv[4], xv[8];
#pragma unroll
      for (int i = 0; i < 4; ++i) wv[i] = Wsh[ty * 4 + i][mm];
#pragma unroll
      for (int j = 0; j < 8; ++j) xv[j] = Xsh[tx + 16 * j][mm];
#pragma unroll
      for (int i = 0; i < 4; ++i)
#pragma unroll
        for (int j = 0; j < 8; ++j) acc[i][j] = __fmaf_rn(wv[i], xv[j], acc[i][j]);
    }
  }
  // store transposed: Gx[lt][e][k], float4 over k
#pragma unroll
  for (int j = 0; j < 8; ++j) {
    float4 v = make_float4(acc[0][j], acc[1][j], acc[2][j], acc[3][j]);
    *(float4*)(Gx + ((size_t)lt * E_EDGES + tx + 16 * j) * G4 + k0 + ty * 4) = v;
  }
}

// ---------------- recurrence (cooperative, flag-barrier per dir) ------
__global__ __launch_bounds__(TPB) void recur_kernel(
    const float* __restrict__ GxF, const float* __restrict__ GxB,
    const float* __restrict__ WhhF, const float* __restrict__ WhhB,
    const int* __restrict__ src, const int* __restrict__ dst,
    const float* __restrict__ cS, const float* __restrict__ cD,
    float* hnG, float* cnG, float* outBase,
    int t0, int nsteps, int roundBase, int* flags) {
  __shared__ float hnS[NN][257];  // row-major node h, odd stride
  __shared__ float Ws[32][257];   // Whh slice rows gc = g*8+jj, row-major over k
  __shared__ float zF[NN][33];
  __shared__ float cnL[NN][9];
  __shared__ float hAcc[NN][9];
  __shared__ float cAcc[NN][9];

  const int tid = threadIdx.x;
  const int wg = blockIdx.x;
  const int dir = wg >> 5;
  const int slot = wg & 31;
  const int j0 = slot * 8;
  const float* Gx = dir ? GxB : GxF;
  const float* Whh = dir ? WhhB : WhhF;
  const int* seA = dir ? dst : src;
  const int* deA = dir ? src : dst;
  const float* cA = dir ? cS : cD;
  float* cnGd = cnG + (size_t)dir * NN * HH;

  // --- stage Whh slice rows (row-major, once) ---
  {
    int gc = tid >> 3, cb = (tid & 7) * 32;
    const float* wr = Whh + ((size_t)(gc >> 3) * HH + j0 + (gc & 7)) * HH + cb;
#pragma unroll
    for (int p = 0; p < 8; ++p) {
      float4 v = *(const float4*)(wr + p * 4);
      *(float4*)(&Ws[gc][cb + p * 4]) = v;
    }
  }
  { // cell state + accumulators
    int n = tid >> 3, jj = tid & 7;
    cnL[n][jj] = cnGd[n * HH + j0 + jj];
    hAcc[n][jj] = 0.f; cAcc[n][jj] = 0.f;
  }
  __syncthreads();

  const int a = tid & 15;    // z: rows 2a, 2a+1
  const int bq = tid >> 4;   // z: gc cols 2bq, 2bq+1
  const int e = tid >> 1, jh = tid & 1;  // edge phase

  for (int rl = 0; rl < nsteps; ++rl) {
    const int r = t0 + rl;
    const int tv = dir ? (T_STEPS - 1 - r) : r;

    // --- issue all flag-independent loads first (latency hides under poll) ---
    const int sec = seA[tv * E_EDGES + e];
    const int dec = deA[tv * E_EDGES + e];
    const float cntc = cA[tv * NN + (tid >> 3)];
    const float* gxe = Gx + ((size_t)rl * E_EDGES + e) * G4 + j0 + jh * 4;
    float4 gxi = *(const float4*)(gxe + 0 * HH);
    float4 gxf = *(const float4*)(gxe + 1 * HH);
    float4 gxg = *(const float4*)(gxe + 2 * HH);
    float4 gxo = *(const float4*)(gxe + 3 * HH);

    // --- poll direction's 32 flags (skip step 0 of dispatch) ---
    if (rl > 0 && tid < 64) {
      const int target = roundBase + rl;
      const int need = (tid < 32);
      int* fp = flags + (dir * 32 + (need ? tid : 0)) * FSTRIDE;
      int guard = 0;
      for (;;) {
        int fv = __hip_atomic_load(fp, __ATOMIC_ACQUIRE, __HIP_MEMORY_SCOPE_AGENT);
        if (__all(!need || fv >= target)) break;
        __builtin_amdgcn_s_sleep(1);
        if (++guard > (1 << 22)) break;
      }
    }
    __syncthreads();

    // --- stage hn (row-major float4 copy) from parity buffer ---
    {
      const float* hnRd = hnG + (size_t)((r & 1) * 2 + dir) * NN * HH;
#pragma unroll
      for (int p = 0; p < 8; ++p) {
        int idx = tid + 256 * p;      // float4 index, 2048 total
        int n = idx >> 6, c4 = idx & 63;
        float4 v = *(const float4*)(hnRd + n * HH + c4 * 4);
        *(float4*)(&hnS[n][c4 * 4]) = v;
      }
    }
    __syncthreads();

    // --- z = hn @ Whh_slice^T : 2x2 register block, b128 LDS reads ---
    {
      float acc00 = 0.f, acc01 = 0.f, acc10 = 0.f, acc11 = 0.f;
      const int n0 = 2 * a, gc0 = 2 * bq;
#pragma unroll 8
      for (int k0 = 0; k0 < HH; k0 += 4) {
        float4 h0 = *(const float4*)(&hnS[n0][k0]);
        float4 h1 = *(const float4*)(&hnS[n0 + 1][k0]);
        float4 w0 = *(const float4*)(&Ws[gc0][k0]);
        float4 w1 = *(const float4*)(&Ws[gc0 + 1][k0]);
        acc00 = __fmaf_rn(h0.x, w0.x, acc00); acc00 = __fmaf_rn(h0.y, w0.y, acc00);
        acc00 = __fmaf_rn(h0.z, w0.z, acc00); acc00 = __fmaf_rn(h0.w, w0.w, acc00);
        acc01 = __fmaf_rn(h0.x, w1.x, acc01); acc01 = __fmaf_rn(h0.y, w1.y, acc01);
        acc01 = __fmaf_rn(h0.z, w1.z, acc01); acc01 = __fmaf_rn(h0.w, w1.w, acc01);
        acc10 = __fmaf_rn(h1.x, w0.x, acc10); acc10 = __fmaf_rn(h1.y, w0.y, acc10);
        acc10 = __fmaf_rn(h1.z, w0.z, acc10); acc10 = __fmaf_rn(h1.w, w0.w, acc10);
        acc11 = __fmaf_rn(h1.x, w1.x, acc11); acc11 = __fmaf_rn(h1.y, w1.y, acc11);
        acc11 = __fmaf_rn(h1.z, w1.z, acc11); acc11 = __fmaf_rn(h1.w, w1.w, acc11);
      }
      zF[n0][gc0] = acc00; zF[n0][gc0 + 1] = acc01;
      zF[n0 + 1][gc0] = acc10; zF[n0 + 1][gc0 + 1] = acc11;
    }
    __syncthreads();

    // --- edge phase: gates -> cell -> per-edge h ---
    {
      const float* zr = zF[sec];
      const float* cr = cnL[sec];
      const float gi4[4] = {gxi.x, gxi.y, gxi.z, gxi.w};
      const float gf4[4] = {gxf.x, gxf.y, gxf.z, gxf.w};
      const float gg4[4] = {gxg.x, gxg.y, gxg.z, gxg.w};
      const float go4[4] = {gxo.x, gxo.y, gxo.z, gxo.w};
      float hq[4];
#pragma unroll
      for (int u = 0; u < 4; ++u) {
        int jj = jh * 4 + u;
        float gi = gi4[u] + zr[0 + jj];
        float gf = gf4[u] + zr[8 + jj];
        float gg = gg4[u] + zr[16 + jj];
        float go = go4[u] + zr[24 + jj];
        float cv = fsig(gf) * cr[jj] + fsig(gi) * ftanh(gg);
        float hv = fsig(go) * ftanh(cv);
        hq[u] = hv;
        atomicAdd(&hAcc[dec][jj], hv);
        atomicAdd(&cAcc[dec][jj], cv);
      }
      int tw = dir ? (T_STEPS - 1 - r) : r;
      *(float4*)(outBase + ((size_t)tw * E_EDGES + e) * 512 + dir * 256 + j0 + jh * 4)
          = make_float4(hq[0], hq[1], hq[2], hq[3]);
    }
    __syncthreads();

    // --- scatter-mean -> write next-parity hn, update cn ---
    {
      int n = tid >> 3, jj = tid & 7;
      float* hnWr = hnG + (size_t)(((r + 1) & 1) * 2 + dir) * NN * HH;
      float denom = fmaxf(cntc, 1.f);
      hnWr[n * HH + j0 + jj] = hAcc[n][jj] / denom;
      cnL[n][jj] = cAcc[n][jj] / denom;
      hAcc[n][jj] = 0.f; cAcc[n][jj] = 0.f;
    }
    __threadfence();
    __syncthreads();
    if (tid == 0) {
      __hip_atomic_store(flags + (dir * 32 + slot) * FSTRIDE, roundBase + rl + 1,
                         __ATOMIC_RELEASE, __HIP_MEMORY_SCOPE_AGENT);
    }
  }

  { // persist cell state for next chunk
    int n = tid >> 3, jj = tid & 7;
    cnGd[n * HH + j0 + jj] = cnL[n][jj];
  }
}

// ---------------- host launcher ---------------------------------------
extern "C" void kernel_launch(void* const* d_in, const int* in_sizes, int n_in,
                              void* d_out, int out_size, void* d_ws, size_t ws_size,
                              hipStream_t stream) {
  const float* x = (const float*)d_in[0];
  const float* Wih0 = (const float*)d_in[1];
  const float* Whh0 = (const float*)d_in[2];
  const float* b0 = (const float*)d_in[3];
  const float* Wih1 = (const float*)d_in[4];
  const float* Whh1 = (const float*)d_in[5];
  const float* b1 = (const float*)d_in[6];
  const int* src = (const int*)d_in[7];
  const int* dst = (const int*)d_in[8];
  float* out = (float*)d_out;

  const size_t outElems = (size_t)T_STEPS * E_EDGES * 512;
  int C = 512;
  while (C >= 1) {
    size_t need = (2 * (size_t)C * G4 * E_EDGES + outElems + 6 * (size_t)NN * HH +
                   2 * (size_t)T_STEPS * NN + NWG * FSTRIDE + 256) * sizeof(float);
    if (need <= ws_size) break;
    C >>= 1;
  }
  if (C < 1) return;

  float* GxF = (float*)d_ws;
  float* GxB = GxF + (size_t)C * G4 * E_EDGES;
  float* out0 = GxB + (size_t)C * G4 * E_EDGES;
  float* hnG = out0 + outElems;                 // 4 * NN*HH (2 parities x 2 dirs)
  float* cnG = hnG + 4 * NN * HH;               // 2 * NN*HH
  float* cSt = cnG + 2 * NN * HH;
  float* cDt = cSt + (size_t)T_STEPS * NN;
  int* flags = (int*)(cDt + (size_t)T_STEPS * NN);

  hipMemsetAsync(flags, 0, NWG * FSTRIDE * sizeof(int), stream);
  count_kernel<<<dim3(T_STEPS), 128, 0, stream>>>(src, dst, cSt, cDt);

  for (int layer = 0; layer < 2; ++layer) {
    const float* Wih = layer ? Wih1 : Wih0;
    const float* Whh = layer ? Whh1 : Whh0;
    const float* bb = layer ? b1 : b0;
    const float* In = layer ? out0 : x;
    float* outT = layer ? out : out0;
    hipMemsetAsync(hnG, 0, 4 * NN * HH * sizeof(float), stream);
    hipMemsetAsync(cnG, 0, 2 * NN * HH * sizeof(float), stream);
    for (int t0 = 0; t0 < T_STEPS; t0 += C) {
      if (layer == 0) {
        gates_gemm<64><<<dim3(16, C), 256, 0, stream>>>(In, Wih, bb, GxF, 0, t0);
        gates_gemm<64><<<dim3(16, C), 256, 0, stream>>>(In, Wih + (size_t)G4 * 64, bb + G4, GxB, 1, t0);
      } else {
        gates_gemm<512><<<dim3(16, C), 256, 0, stream>>>(In, Wih, bb, GxF, 0, t0);
        gates_gemm<512><<<dim3(16, C), 256, 0, stream>>>(In, Wih + (size_t)G4 * 512, bb + G4, GxB, 1, t0);
      }
      const float* gxF = GxF; const float* gxB = GxB;
      const float* whF = Whh; const float* whB = Whh + (size_t)G4 * HH;
      const int* psrc = src; const int* pdst = dst;
      const float* pcS = cSt; const float* pcD = cDt;
      float* phn = hnG; float* pcn = cnG; float* pout = outT;
      int a_t0 = t0, a_ns = C, a_rb = layer * T_STEPS + t0;
      int* pfl = flags;
      void* args[15] = {&gxF, &gxB, &whF, &whB, &psrc, &pdst, &pcS, &pcD,
                        &phn, &pcn, &pout, &a_t0, &a_ns, &a_rb, &pfl};
      hipLaunchCooperativeKernel((const void*)recur_kernel, dim3(NWG), dim3(TPB),
                                 args, 0, stream);
    }
  }
}

// Round 5
// 13715.038 us; speedup vs baseline: 1.6829x; 1.5212x over previous
//
#include <hip/hip_runtime.h>

#define T_STEPS 512
#define E_EDGES 128
#define NN 32
#define HH 256
#define G4 1024   // 4*H
#define NWG 64    // 2 dirs * 32 slots
#define TPB 256
#define FSTRIDE 16  // ints between flags (64B cachelines)

__device__ __forceinline__ float fsig(float x) {
  x = fminf(fmaxf(x, -30.f), 30.f);
  return 1.f / (1.f + __expf(-x));
}
__device__ __forceinline__ float ftanh(float x) {
  float xc = fminf(fmaxf(x, -15.f), 15.f);
  float e = __expf(2.f * xc);
  return (e - 1.f) / (e + 1.f);
}

// ---------------- per-step edge counts (denominators) ----------------
__global__ __launch_bounds__(128) void count_kernel(const int* __restrict__ src,
    const int* __restrict__ dst, float* __restrict__ cS, float* __restrict__ cD) {
  __shared__ int ls[NN], ld[NN];
  int t = blockIdx.x;
  if (threadIdx.x < NN) { ls[threadIdx.x] = 0; ld[threadIdx.x] = 0; }
  __syncthreads();
  atomicAdd(&ls[src[t * E_EDGES + threadIdx.x]], 1);
  atomicAdd(&ld[dst[t * E_EDGES + threadIdx.x]], 1);
  __syncthreads();
  if (threadIdx.x < NN) {
    cS[t * NN + threadIdx.x] = (float)ls[threadIdx.x];
    cD[t * NN + threadIdx.x] = (float)ld[threadIdx.x];
  }
}

// ---------------- feed-forward gates GEMM -----------------------------
// Gx[lt][e][k] = b[k] + sum_m In[tsrc][e][m] * W[k][m]   ([e][k] layout)
template <int M>
__global__ __launch_bounds__(256) void gates_gemm(
    const float* __restrict__ In, const float* __restrict__ W,
    const float* __restrict__ b, float* __restrict__ Gx, int reverse, int t0) {
  __shared__ float Wsh[64][68];
  __shared__ float Xsh[128][68];
  const int tid = threadIdx.x;
  const int k0 = blockIdx.x * 64;
  const int lt = blockIdx.y;
  const int t = t0 + lt;
  const int tsrc = reverse ? (T_STEPS - 1 - t) : t;
  const float* Inb = In + (size_t)tsrc * E_EDGES * M;

  const int ty = tid >> 4;
  const int tx = tid & 15;

  float acc[4][8];
#pragma unroll
  for (int i = 0; i < 4; ++i) {
    float bv = b[k0 + ty * 4 + i];
#pragma unroll
    for (int j = 0; j < 8; ++j) acc[i][j] = bv;
  }

  for (int m0 = 0; m0 < M; m0 += 64) {
    __syncthreads();
#pragma unroll
    for (int p = 0; p < 4; ++p) {
      int r = (tid >> 4) + 16 * p;
      int c4 = tid & 15;
      float4 v = *(const float4*)(W + (size_t)(k0 + r) * M + m0 + c4 * 4);
      *(float4*)(&Wsh[r][c4 * 4]) = v;
    }
#pragma unroll
    for (int p = 0; p < 8; ++p) {
      int r = (tid >> 4) + 16 * p;
      int c4 = tid & 15;
      float4 v = *(const float4*)(Inb + (size_t)r * M + m0 + c4 * 4);
      *(float4*)(&Xsh[r][c4 * 4]) = v;
    }
    __syncthreads();
#pragma unroll 8
    for (int mm = 0; mm < 64; ++mm) {
      float wv[4], xv[8];
#pragma unroll
      for (int i = 0; i < 4; ++i) wv[i] = Wsh[ty * 4 + i][mm];
#pragma unroll
      for (int j = 0; j < 8; ++j) xv[j] = Xsh[tx + 16 * j][mm];
#pragma unroll
      for (int i = 0; i < 4; ++i)
#pragma unroll
        for (int j = 0; j < 8; ++j) acc[i][j] = __fmaf_rn(wv[i], xv[j], acc[i][j]);
    }
  }
#pragma unroll
  for (int j = 0; j < 8; ++j) {
    float4 v = make_float4(acc[0][j], acc[1][j], acc[2][j], acc[3][j]);
    *(float4*)(Gx + ((size_t)lt * E_EDGES + tx + 16 * j) * G4 + k0 + ty * 4) = v;
  }
}

// ---------------- recurrence (cooperative, light-fence flag barrier) --
__global__ __launch_bounds__(TPB) void recur_kernel(
    const float* __restrict__ GxF, const float* __restrict__ GxB,
    const float* __restrict__ WhhF, const float* __restrict__ WhhB,
    const int* __restrict__ src, const int* __restrict__ dst,
    const float* __restrict__ cS, const float* __restrict__ cD,
    float* hnG, float* cnG, float* outBase,
    int t0, int nsteps, int roundBase, int* flags) {
  // XOR-swizzled float4 LDS: slot = row*64 + (c4 ^ (row>>2)) -> 16B aligned,
  // conflict-free for the z-phase 4-row broadcast-group reads.
  __shared__ float4 hnS4[NN * 64];   // 32 KB  (hn, rows = node)
  __shared__ float4 Ws4[32 * 64];    // 32 KB  (Whh slice, rows = gc)
  __shared__ float zP[4][NN][33];    // K-split partials
  __shared__ float zF[NN][33];
  __shared__ float cnL[NN][9];
  __shared__ float hAcc[NN][9];
  __shared__ float cAcc[NN][9];

  const int tid = threadIdx.x;
  const int wg = blockIdx.x;
  const int dir = wg >> 5;
  const int slot = wg & 31;
  const int j0 = slot * 8;
  const float* Gx = dir ? GxB : GxF;
  const float* Whh = dir ? WhhB : WhhF;
  const int* seA = dir ? dst : src;
  const int* deA = dir ? src : dst;
  const float* cA = dir ? cS : cD;
  float* cnGd = cnG + (size_t)dir * NN * HH;

  // --- stage Whh slice (swizzled), once ---
  {
    int gc = tid >> 3;                       // 0..31
    int g = gc >> 3, jj = gc & 7;
    const float* wr = Whh + ((size_t)(g * HH) + j0 + jj) * HH;
    int c0 = (tid & 7) * 8;
#pragma unroll
    for (int p = 0; p < 8; ++p) {
      int c4 = c0 + p;
      Ws4[gc * 64 + (c4 ^ (gc >> 2))] = *(const float4*)(wr + c4 * 4);
    }
  }
  { // cell state + accumulators
    int n = tid >> 3, jj = tid & 7;
    cnL[n][jj] = cnGd[n * HH + j0 + jj];
    hAcc[n][jj] = 0.f; cAcc[n][jj] = 0.f;
  }
  __syncthreads();

  const int lane = tid & 63;
  const int wv = tid >> 6;       // wave -> K range [wv*64, +64)
  const int ng = lane >> 3;      // nodes 4ng..4ng+3
  const int gg = lane & 7;       // gc 4gg..4gg+3
  const int e = tid >> 1, jh = tid & 1;  // edge phase

  for (int rl = 0; rl < nsteps; ++rl) {
    const int r = t0 + rl;
    const int tv = dir ? (T_STEPS - 1 - r) : r;

    // --- P0: issue step-invariant loads (hide latency under poll) ---
    const int sec = seA[tv * E_EDGES + e];
    const int dec = deA[tv * E_EDGES + e];
    const float cntc = cA[tv * NN + (tid >> 3)];
    const float* gxe = Gx + ((size_t)rl * E_EDGES + e) * G4 + j0 + jh * 4;
    float4 gxi = *(const float4*)(gxe + 0 * HH);
    float4 gxf = *(const float4*)(gxe + 1 * HH);
    float4 gxg = *(const float4*)(gxe + 2 * HH);
    float4 gxo = *(const float4*)(gxe + 3 * HH);

    // --- P1: poll (relaxed spin, ONE acquire fence after) ---
    if (rl > 0) {
      if (tid < 64) {
        const int target = roundBase + rl;
        int* fp = flags + (dir * 32 + (tid & 31)) * FSTRIDE;
        int guard = 0;
        for (;;) {
          int fv = __hip_atomic_load(fp, __ATOMIC_RELAXED, __HIP_MEMORY_SCOPE_AGENT);
          if (__all(fv >= target)) break;
          __builtin_amdgcn_s_sleep(1);
          if (++guard > (1 << 22)) break;
        }
      }
      if (tid == 0)
        __builtin_amdgcn_fence(__ATOMIC_ACQUIRE, "agent");
    }
    __syncthreads();

    // --- P2: stage hn (swizzled float4) from parity buffer ---
    {
      const float* hnRd = hnG + (size_t)((r & 1) * 2 + dir) * NN * HH;
#pragma unroll
      for (int p = 0; p < 8; ++p) {
        int idx = tid + 256 * p;  // 0..2047
        int n = idx >> 6, c4 = idx & 63;
        hnS4[n * 64 + (c4 ^ (n >> 2))] = *(const float4*)(hnRd + n * HH + c4 * 4);
      }
    }
    __syncthreads();

    // --- P3: z partials, 4x4 block, K-split across 4 waves ---
    {
      float za[4][4];
#pragma unroll
      for (int i = 0; i < 4; ++i)
#pragma unroll
        for (int j = 0; j < 4; ++j) za[i][j] = 0.f;
      const int kb = wv * 16;
#pragma unroll 4
      for (int c4 = kb; c4 < kb + 16; ++c4) {
        float4 h[4], w[4];
#pragma unroll
        for (int i = 0; i < 4; ++i) h[i] = hnS4[(4 * ng + i) * 64 + (c4 ^ ng)];
#pragma unroll
        for (int j = 0; j < 4; ++j) w[j] = Ws4[(4 * gg + j) * 64 + (c4 ^ gg)];
#pragma unroll
        for (int i = 0; i < 4; ++i)
#pragma unroll
          for (int j = 0; j < 4; ++j) {
            za[i][j] = __fmaf_rn(h[i].x, w[j].x, za[i][j]);
            za[i][j] = __fmaf_rn(h[i].y, w[j].y, za[i][j]);
            za[i][j] = __fmaf_rn(h[i].z, w[j].z, za[i][j]);
            za[i][j] = __fmaf_rn(h[i].w, w[j].w, za[i][j]);
          }
      }
#pragma unroll
      for (int i = 0; i < 4; ++i)
#pragma unroll
        for (int j = 0; j < 4; ++j) zP[wv][4 * ng + i][4 * gg + j] = za[i][j];
    }
    __syncthreads();

    // --- P4: reduce partials -> zF ---
    {
      int n = tid >> 3, c0 = (tid & 7) * 4;
#pragma unroll
      for (int u = 0; u < 4; ++u) {
        zF[n][c0 + u] = zP[0][n][c0 + u] + zP[1][n][c0 + u] +
                        zP[2][n][c0 + u] + zP[3][n][c0 + u];
      }
    }
    __syncthreads();

    // --- P5: edge phase: gates -> cell -> per-edge h ---
    {
      const float* zr = zF[sec];
      const float* cr = cnL[sec];
      const float gi4[4] = {gxi.x, gxi.y, gxi.z, gxi.w};
      const float gf4[4] = {gxf.x, gxf.y, gxf.z, gxf.w};
      const float gg4[4] = {gxg.x, gxg.y, gxg.z, gxg.w};
      const float go4[4] = {gxo.x, gxo.y, gxo.z, gxo.w};
      float hq[4];
#pragma unroll
      for (int u = 0; u < 4; ++u) {
        int jj = jh * 4 + u;
        float gi = gi4[u] + zr[0 + jj];
        float gf = gf4[u] + zr[8 + jj];
        float gv = gg4[u] + zr[16 + jj];
        float go = go4[u] + zr[24 + jj];
        float cv = fsig(gf) * cr[jj] + fsig(gi) * ftanh(gv);
        float hv = fsig(go) * ftanh(cv);
        hq[u] = hv;
        atomicAdd(&hAcc[dec][jj], hv);
        atomicAdd(&cAcc[dec][jj], cv);
      }
      int tw = dir ? (T_STEPS - 1 - r) : r;
      *(float4*)(outBase + ((size_t)tw * E_EDGES + e) * 512 + dir * 256 + j0 + jh * 4)
          = make_float4(hq[0], hq[1], hq[2], hq[3]);
    }
    __syncthreads();

    // --- P6: scatter-mean -> next-parity hn; ONE release fence + flag ---
    {
      int n = tid >> 3, jj = tid & 7;
      float* hnWr = hnG + (size_t)(((r + 1) & 1) * 2 + dir) * NN * HH;
      float rd = 1.f / fmaxf(cntc, 1.f);
      hnWr[n * HH + j0 + jj] = hAcc[n][jj] * rd;
      cnL[n][jj] = cAcc[n][jj] * rd;
      hAcc[n][jj] = 0.f; cAcc[n][jj] = 0.f;
    }
    __syncthreads();   // drains hn stores for the whole WG
    if (tid == 0) {
      __builtin_amdgcn_fence(__ATOMIC_RELEASE, "agent");
      __hip_atomic_store(flags + (dir * 32 + slot) * FSTRIDE, roundBase + rl + 1,
                         __ATOMIC_RELAXED, __HIP_MEMORY_SCOPE_AGENT);
    }
  }

  { // persist cell state for next chunk
    int n = tid >> 3, jj = tid & 7;
    cnGd[n * HH + j0 + jj] = cnL[n][jj];
  }
}

// ---------------- host launcher ---------------------------------------
extern "C" void kernel_launch(void* const* d_in, const int* in_sizes, int n_in,
                              void* d_out, int out_size, void* d_ws, size_t ws_size,
                              hipStream_t stream) {
  const float* x = (const float*)d_in[0];
  const float* Wih0 = (const float*)d_in[1];
  const float* Whh0 = (const float*)d_in[2];
  const float* b0 = (const float*)d_in[3];
  const float* Wih1 = (const float*)d_in[4];
  const float* Whh1 = (const float*)d_in[5];
  const float* b1 = (const float*)d_in[6];
  const int* src = (const int*)d_in[7];
  const int* dst = (const int*)d_in[8];
  float* out = (float*)d_out;

  const size_t outElems = (size_t)T_STEPS * E_EDGES * 512;
  int C = 512;
  while (C >= 1) {
    size_t need = (2 * (size_t)C * G4 * E_EDGES + outElems + 6 * (size_t)NN * HH +
                   2 * (size_t)T_STEPS * NN + NWG * FSTRIDE + 256) * sizeof(float);
    if (need <= ws_size) break;
    C >>= 1;
  }
  if (C < 1) return;

  float* GxF = (float*)d_ws;
  float* GxB = GxF + (size_t)C * G4 * E_EDGES;
  float* out0 = GxB + (size_t)C * G4 * E_EDGES;
  float* hnG = out0 + outElems;                 // 4 * NN*HH (2 parities x 2 dirs)
  float* cnG = hnG + 4 * NN * HH;               // 2 * NN*HH
  float* cSt = cnG + 2 * NN * HH;
  float* cDt = cSt + (size_t)T_STEPS * NN;
  int* flags = (int*)(cDt + (size_t)T_STEPS * NN);

  (void)hipMemsetAsync(flags, 0, NWG * FSTRIDE * sizeof(int), stream);
  count_kernel<<<dim3(T_STEPS), 128, 0, stream>>>(src, dst, cSt, cDt);

  for (int layer = 0; layer < 2; ++layer) {
    const float* Wih = layer ? Wih1 : Wih0;
    const float* Whh = layer ? Whh1 : Whh0;
    const float* bb = layer ? b1 : b0;
    const float* In = layer ? out0 : x;
    float* outT = layer ? out : out0;
    (void)hipMemsetAsync(hnG, 0, 4 * NN * HH * sizeof(float), stream);
    (void)hipMemsetAsync(cnG, 0, 2 * NN * HH * sizeof(float), stream);
    for (int t0 = 0; t0 < T_STEPS; t0 += C) {
      if (layer == 0) {
        gates_gemm<64><<<dim3(16, C), 256, 0, stream>>>(In, Wih, bb, GxF, 0, t0);
        gates_gemm<64><<<dim3(16, C), 256, 0, stream>>>(In, Wih + (size_t)G4 * 64, bb + G4, GxB, 1, t0);
      } else {
        gates_gemm<512><<<dim3(16, C), 256, 0, stream>>>(In, Wih, bb, GxF, 0, t0);
        gates_gemm<512><<<dim3(16, C), 256, 0, stream>>>(In, Wih + (size_t)G4 * 512, bb + G4, GxB, 1, t0);
      }
      const float* gxF = GxF; const float* gxB = GxB;
      const float* whF = Whh; const float* whB = Whh + (size_t)G4 * HH;
      const int* psrc = src; const int* pdst = dst;
      const float* pcS = cSt; const float* pcD = cDt;
      float* phn = hnG; float* pcn = cnG; float* pout = outT;
      int a_t0 = t0, a_ns = C, a_rb = layer * T_STEPS + t0;
      int* pfl = flags;
      void* args[15] = {&gxF, &gxB, &whF, &whB, &psrc, &pdst, &pcS, &pcD,
                        &phn, &pcn, &pout, &a_t0, &a_ns, &a_rb, &pfl};
      hipLaunchCooperativeKernel((const void*)recur_kernel, dim3(NWG), dim3(TPB),
                                 args, 0, stream);
    }
  }
}